// Round 2
// baseline (2125.808 us; speedup 1.0000x reference)
//
#include <hip/hip_runtime.h>

typedef unsigned short bf16_t;
typedef __attribute__((ext_vector_type(8))) short short8;
typedef __attribute__((ext_vector_type(4))) float f32x4;

#define S_LEN 2048
#define HID 7168
#define NHEAD 32
#define QLORA 1536
#define KVLORA 512
#define ROPE_DIM 64
#define KFULL 576
#define KFULLP 640
#define V_DIM 128
#define OUTW 4096
#define SM_SCALE 0.07216878364870323f   /* 1/sqrt(192) */
#define LN10000 9.210340371976184f

__device__ __forceinline__ bf16_t f2bf(float x) {
  unsigned int u = __float_as_uint(x);
  u += 0x7fffu + ((u >> 16) & 1u);
  return (bf16_t)(u >> 16);
}

__device__ __forceinline__ void store_out(float* p, float v) { *p = v; }
__device__ __forceinline__ void store_out(bf16_t* p, float v) { *p = f2bf(v); }

// async global->LDS, 16B per lane; lds dest must be wave-uniform base (HW adds lane*16)
__device__ __forceinline__ void gl_lds16(const bf16_t* g, bf16_t* l) {
  __builtin_amdgcn_global_load_lds(
      (const __attribute__((address_space(1))) void*)g,
      (__attribute__((address_space(3))) void*)l, 16, 0, 0);
}

// ---------------- GEMM: C[M,N] = A[M,K] @ BT[N,K]^T, 128x128 tile, 4 waves ----------------
// flags bit0: causal tile skip (skip if n0 >= m0+128)   [QK^T]
// flags bit1: causal K cap (Ke = min(K, m0+128))         [PV: probs cols > row are 0]
template<typename CT>
__global__ __launch_bounds__(256) void gemm_bt(
    const bf16_t* __restrict__ A, int lda, long sA,
    const bf16_t* __restrict__ BT, int ldb, long sB,
    CT* __restrict__ C, int ldc, long sC,
    int K, int flags)
{
  __shared__ bf16_t As[128 * 32];
  __shared__ bf16_t Bs[128 * 32];
  const int tid = threadIdx.x;
  const int wid = tid >> 6;
  const int lane = tid & 63;
  const long m0 = (long)blockIdx.y * 128;
  const long n0 = (long)blockIdx.x * 128;
  if ((flags & 1) && n0 >= m0 + 128) return;
  const int z = blockIdx.z;
  A  += (long)z * sA;
  BT += (long)z * sB;
  C  += (long)z * sC;
  int Ke = K;
  if (flags & 2) { int cap = (int)m0 + 128; Ke = cap < K ? cap : K; }

  const int wr = wid >> 1, wc = wid & 1;
  const int srow = lane >> 2;         // 0..15
  const int scol = (lane & 3) * 8;    // 0,8,16,24
  const int frow = lane & 15;
  const int fcol = (lane >> 4) * 8;

  f32x4 acc[4][4];
#pragma unroll
  for (int m = 0; m < 4; ++m)
#pragma unroll
    for (int n = 0; n < 4; ++n) acc[m][n] = (f32x4){0.f, 0.f, 0.f, 0.f};

  const bf16_t* Abase = A + m0 * lda;
  const bf16_t* Bbase = BT + n0 * ldb;

  for (int k0 = 0; k0 < Ke; k0 += 32) {
#pragma unroll
    for (int i = 0; i < 2; ++i) {
      const int r = wid * 32 + i * 16;  // wave-uniform LDS row base (16 rows = 1024B)
      gl_lds16(Abase + (long)(r + srow) * lda + k0 + scol, &As[r * 32]);
      gl_lds16(Bbase + (long)(r + srow) * ldb + k0 + scol, &Bs[r * 32]);
    }
    __syncthreads();
    short8 af[4], bfr[4];
#pragma unroll
    for (int m = 0; m < 4; ++m)
      af[m] = *(const short8*)&As[(wr * 64 + m * 16 + frow) * 32 + fcol];
#pragma unroll
    for (int n = 0; n < 4; ++n)
      bfr[n] = *(const short8*)&Bs[(wc * 64 + n * 16 + frow) * 32 + fcol];
#pragma unroll
    for (int m = 0; m < 4; ++m)
#pragma unroll
      for (int n = 0; n < 4; ++n)
        acc[m][n] = __builtin_amdgcn_mfma_f32_16x16x32_bf16(af[m], bfr[n], acc[m][n], 0, 0, 0);
    __syncthreads();
  }

  const int crow = (lane >> 4) * 4;
  const int ccol = lane & 15;
#pragma unroll
  for (int m = 0; m < 4; ++m)
#pragma unroll
    for (int n = 0; n < 4; ++n) {
      long row = m0 + wr * 64 + m * 16 + crow;
      long col = n0 + wc * 64 + n * 16 + ccol;
#pragma unroll
      for (int r = 0; r < 4; ++r)
        store_out(&C[(row + r) * ldc + col], acc[m][n][r]);
    }
}

// ---------------- transpose-convert f32 [R][C] -> bf16 [Cout][R] (rows >= C zero-filled) ----
__global__ __launch_bounds__(256) void trans_f32_bf16(
    const float* __restrict__ in, bf16_t* __restrict__ out, int R, int C, int Cout)
{
  __shared__ float t[32][33];
  const long z = blockIdx.z;
  in  += z * (long)R * C;
  out += z * (long)Cout * R;
  const int r0 = blockIdx.x * 32, c0 = blockIdx.y * 32;
  const int tx = threadIdx.x & 31, ty = threadIdx.x >> 5;
#pragma unroll
  for (int i = 0; i < 4; ++i) {
    int r = r0 + ty + i * 8, c = c0 + tx;
    float v = 0.f;
    if (r < R && c < C) v = in[(long)r * C + c];
    t[ty + i * 8][tx] = v;
  }
  __syncthreads();
#pragma unroll
  for (int i = 0; i < 4; ++i) {
    int orow = c0 + ty + i * 8, ocol = r0 + tx;
    if (orow < Cout && ocol < R) out[(long)orow * R + ocol] = f2bf(t[tx][ty + i * 8]);
  }
}

// bf16 [R rows of ldin, first C cols] -> bf16 [C][ldout]
__global__ __launch_bounds__(256) void trans_bf16(
    const bf16_t* __restrict__ in, int ldin, bf16_t* __restrict__ out, int ldout, int R, int C)
{
  __shared__ bf16_t t[32][33];
  const int r0 = blockIdx.x * 32, c0 = blockIdx.y * 32;
  const int tx = threadIdx.x & 31, ty = threadIdx.x >> 5;
#pragma unroll
  for (int i = 0; i < 4; ++i) {
    int r = r0 + ty + i * 8, c = c0 + tx;
    t[ty + i * 8][tx] = (r < R && c < C) ? in[(long)r * ldin + c] : (bf16_t)0;
  }
  __syncthreads();
#pragma unroll
  for (int i = 0; i < 4; ++i) {
    int orow = c0 + ty + i * 8, ocol = r0 + tx;
    if (orow < C && ocol < R) out[(long)orow * ldout + ocol] = t[tx][ty + i * 8];
  }
}

__global__ __launch_bounds__(256) void cvt_f32_bf16(
    const float* __restrict__ in, bf16_t* __restrict__ out, long n4)
{
  long i = (long)blockIdx.x * 256 + threadIdx.x;
  if (i >= n4) return;
  const float4 v = ((const float4*)in)[i];
  ushort4 o;
  o.x = f2bf(v.x); o.y = f2bf(v.y); o.z = f2bf(v.z); o.w = f2bf(v.w);
  ((ushort4*)out)[i] = o;
}

// ---------------- block reductions (blockDim=256) ----------------
__device__ __forceinline__ float block_sum(float v) {
#pragma unroll
  for (int o = 32; o > 0; o >>= 1) v += __shfl_xor(v, o);
  __shared__ float sh[4];
  __syncthreads();
  if ((threadIdx.x & 63) == 0) sh[threadIdx.x >> 6] = v;
  __syncthreads();
  return sh[0] + sh[1] + sh[2] + sh[3];
}
__device__ __forceinline__ float block_max(float v) {
#pragma unroll
  for (int o = 32; o > 0; o >>= 1) v = fmaxf(v, __shfl_xor(v, o));
  __shared__ float sh[4];
  __syncthreads();
  if ((threadIdx.x & 63) == 0) sh[threadIdx.x >> 6] = v;
  __syncthreads();
  return fmaxf(fmaxf(sh[0], sh[1]), fmaxf(sh[2], sh[3]));
}

__global__ __launch_bounds__(256) void rmsnorm_k(
    const float* __restrict__ in, int ldin, const float* __restrict__ w,
    bf16_t* __restrict__ out, int ldout, int len)
{
  const long r = blockIdx.x;
  const float* x = in + r * ldin;
  float ss = 0.f;
  for (int c = threadIdx.x; c < len; c += 256) { float v = x[c]; ss += v * v; }
  ss = block_sum(ss);
  const float sc = rsqrtf(ss / len + 1e-6f);
  for (int c = threadIdx.x; c < len; c += 256)
    out[r * ldout + c] = f2bf(x[c] * sc * w[c]);
}

// causal row softmax: logits f32 [z][S][S] -> probs bf16 (cols>row = 0), scale folded in
__global__ __launch_bounds__(256) void softmax_causal(
    const float* __restrict__ logits, bf16_t* __restrict__ probs)
{
  __shared__ float buf[S_LEN];
  const int r = blockIdx.x;
  const long z = blockIdx.y;
  const float* L = logits + (z * S_LEN + r) * (long)S_LEN;
  bf16_t* P = probs + (z * S_LEN + r) * (long)S_LEN;
  const int n = r + 1;
  float mx = -1e30f;
  for (int c = threadIdx.x; c < n; c += 256) {
    float v = L[c] * SM_SCALE;
    buf[c] = v;
    mx = fmaxf(mx, v);
  }
  mx = block_max(mx);
  float sum = 0.f;
  for (int c = threadIdx.x; c < n; c += 256) {
    float e = __expf(buf[c] - mx);
    buf[c] = e;
    sum += e;
  }
  sum = block_sum(sum);
  const float inv = 1.f / sum;
  for (int c = threadIdx.x; c < S_LEN; c += 256)
    P[c] = f2bf(c < n ? buf[c] * inv : 0.f);
}

// interleaved RoPE (deinterleave + rotate-half): qpe_raw f32 [S][NH*64] -> qfull[h][s][512..575]
__global__ __launch_bounds__(256) void rope_q_k(
    const float* __restrict__ qpe, const int* __restrict__ pos_ids, bf16_t* __restrict__ qfull)
{
  const int s = blockIdx.x;
  const float pos = (float)pos_ids[s];
  for (int idx = threadIdx.x; idx < NHEAD * 32; idx += 256) {
    const int h = idx >> 5, i = idx & 31;
    const float* xr = qpe + (long)s * 2048 + h * 64;
    float x0 = xr[2 * i], x1 = xr[2 * i + 1];
    float invf = __expf(-(float)(2 * i) * (LN10000 / 64.f));
    float f = pos * invf;
    float cs = cosf(f), sn = sinf(f);
    bf16_t* o = qfull + (long)h * (S_LEN * KFULL) + (long)s * KFULL + KVLORA;
    o[i]      = f2bf(x0 * cs - x1 * sn);
    o[i + 32] = f2bf(x1 * cs + x0 * sn);
  }
}

__global__ void rope_k_k(
    const float* __restrict__ comp, const int* __restrict__ pos_ids, bf16_t* __restrict__ kfull)
{
  const int s = blockIdx.x;
  const int i = threadIdx.x;
  if (i >= 32) return;
  const float pos = (float)pos_ids[s];
  const float* xr = comp + (long)s * KFULLP + KVLORA;
  float x0 = xr[2 * i], x1 = xr[2 * i + 1];
  float invf = __expf(-(float)(2 * i) * (LN10000 / 64.f));
  float f = pos * invf;
  float cs = cosf(f), sn = sinf(f);
  bf16_t* o = kfull + (long)s * KFULL + KVLORA;
  o[i]      = f2bf(x0 * cs - x1 * sn);
  o[i + 32] = f2bf(x1 * cs + x0 * sn);
}

extern "C" void kernel_launch(void* const* d_in, const int* in_sizes, int n_in,
                              void* d_out, int out_size, void* d_ws, size_t ws_size,
                              hipStream_t stream)
{
  const float* hs    = (const float*)d_in[0];
  // d_in[1] = attention_mask (causal triu) — structure used implicitly
  const int*   pos   = (const int*)d_in[2];
  const float* Wkva  = (const float*)d_in[3];
  const float* Wqa   = (const float*)d_in[4];
  const float* qlnw  = (const float*)d_in[5];
  const float* kvlnw = (const float*)d_in[6];
  const float* Wqr   = (const float*)d_in[7];
  const float* fqk   = (const float*)d_in[8];
  const float* vupw  = (const float*)d_in[9];
  const float* Wo    = (const float*)d_in[10];
  float* out = (float*)d_out;
  (void)in_sizes; (void)n_in; (void)out_size; (void)ws_size;

  char* cur = (char*)d_ws;
  auto alloc = [&](size_t bytes) -> void* {
    void* p = (void*)cur;
    cur += (bytes + 255) & ~(size_t)255;
    return p;
  };
  bf16_t* hsB    = (bf16_t*)alloc((size_t)S_LEN * HID * 2);
  bf16_t* WkvaT  = (bf16_t*)alloc((size_t)KFULLP * HID * 2);
  bf16_t* WqaT   = (bf16_t*)alloc((size_t)QLORA * HID * 2);
  bf16_t* WqrT   = (bf16_t*)alloc((size_t)2048 * QLORA * 2);
  bf16_t* fqkT   = (bf16_t*)alloc((size_t)NHEAD * KVLORA * QLORA * 2);
  bf16_t* vupT   = (bf16_t*)alloc((size_t)NHEAD * V_DIM * KVLORA * 2);
  bf16_t* WoT    = (bf16_t*)alloc((size_t)HID * OUTW * 2);
  float*  comp   = (float*)alloc((size_t)S_LEN * KFULLP * 4);
  float*  qaraw  = (float*)alloc((size_t)S_LEN * QLORA * 4);
  bf16_t* qaB    = (bf16_t*)alloc((size_t)S_LEN * QLORA * 2);
  bf16_t* kfull  = (bf16_t*)alloc((size_t)S_LEN * KFULL * 2);
  bf16_t* kvaT   = (bf16_t*)alloc((size_t)KVLORA * S_LEN * 2);
  float*  qperaw = (float*)alloc((size_t)S_LEN * 2048 * 4);
  bf16_t* qfull  = (bf16_t*)alloc((size_t)NHEAD * S_LEN * KFULL * 2);
  float*  logits = (float*)alloc((size_t)4 * S_LEN * S_LEN * 4);
  bf16_t* probs  = (bf16_t*)alloc((size_t)4 * S_LEN * S_LEN * 2);
  bf16_t* attno  = (bf16_t*)alloc((size_t)S_LEN * OUTW * 2);

  // ---- one-shot bf16 conversions; weights stored transposed ([N][K]) for gemm_bt ----
  cvt_f32_bf16<<<(int)(((long)S_LEN * HID / 4 + 255) / 256), 256, 0, stream>>>(hs, hsB, (long)S_LEN * HID / 4);
  trans_f32_bf16<<<dim3(HID / 32, KFULLP / 32, 1), 256, 0, stream>>>(Wkva, WkvaT, HID, KFULL, KFULLP);
  trans_f32_bf16<<<dim3(HID / 32, QLORA / 32, 1), 256, 0, stream>>>(Wqa, WqaT, HID, QLORA, QLORA);
  trans_f32_bf16<<<dim3(QLORA / 32, 2048 / 32, 1), 256, 0, stream>>>(Wqr, WqrT, QLORA, 2048, 2048);
  trans_f32_bf16<<<dim3(QLORA / 32, KVLORA / 32, NHEAD), 256, 0, stream>>>(fqk, fqkT, QLORA, KVLORA, KVLORA);
  trans_f32_bf16<<<dim3(KVLORA / 32, V_DIM / 32, NHEAD), 256, 0, stream>>>(vupw, vupT, KVLORA, V_DIM, V_DIM);
  trans_f32_bf16<<<dim3(OUTW / 32, HID / 32, 1), 256, 0, stream>>>(Wo, WoT, OUTW, HID, HID);

  // ---- latent projections ----
  gemm_bt<float><<<dim3(KFULLP / 128, S_LEN / 128, 1), 256, 0, stream>>>(
      hsB, HID, 0, WkvaT, HID, 0, comp, KFULLP, 0, HID, 0);
  gemm_bt<float><<<dim3(QLORA / 128, S_LEN / 128, 1), 256, 0, stream>>>(
      hsB, HID, 0, WqaT, HID, 0, qaraw, QLORA, 0, HID, 0);

  rmsnorm_k<<<S_LEN, 256, 0, stream>>>(comp, KFULLP, kvlnw, kfull, KFULL, KVLORA);
  rope_k_k<<<S_LEN, 64, 0, stream>>>(comp, pos, kfull);
  rmsnorm_k<<<S_LEN, 256, 0, stream>>>(qaraw, QLORA, qlnw, qaB, QLORA, QLORA);
  trans_bf16<<<dim3(S_LEN / 32, KVLORA / 32, 1), 256, 0, stream>>>(kfull, KFULL, kvaT, S_LEN, S_LEN, KVLORA);

  // ---- q rope path ----
  gemm_bt<float><<<dim3(2048 / 128, S_LEN / 128, 1), 256, 0, stream>>>(
      qaB, QLORA, 0, WqrT, QLORA, 0, qperaw, 2048, 0, QLORA, 0);
  rope_q_k<<<S_LEN, 256, 0, stream>>>(qperaw, pos, qfull);

  // ---- absorbed nope query: dq[h] = qa @ fusedqk[h] -> qfull cols 0..511 ----
  gemm_bt<bf16_t><<<dim3(KVLORA / 128, S_LEN / 128, NHEAD), 256, 0, stream>>>(
      qaB, QLORA, 0, fqkT, QLORA, (long)KVLORA * QLORA, qfull, KFULL, (long)S_LEN * KFULL, QLORA, 0);

  // ---- attention, 4 heads per chunk; ctx overwrites dq region of qfull ----
  for (int ch = 0; ch < 8; ++ch) {
    bf16_t* qh = qfull + (long)ch * 4 * S_LEN * KFULL;
    gemm_bt<float><<<dim3(S_LEN / 128, S_LEN / 128, 4), 256, 0, stream>>>(
        qh, KFULL, (long)S_LEN * KFULL, kfull, KFULL, 0,
        logits, S_LEN, (long)S_LEN * S_LEN, KFULL, /*causal skip*/1);
    softmax_causal<<<dim3(S_LEN, 4, 1), 256, 0, stream>>>(logits, probs);
    gemm_bt<bf16_t><<<dim3(KVLORA / 128, S_LEN / 128, 4), 256, 0, stream>>>(
        probs, S_LEN, (long)S_LEN * S_LEN, kvaT, S_LEN, 0,
        qh, KFULL, (long)S_LEN * KFULL, S_LEN, /*causal K cap*/2);
  }

  // ---- out_h = ctx_h @ v_up[h] -> attno[s][h*128+d] ----
  gemm_bt<bf16_t><<<dim3(V_DIM / 128, S_LEN / 128, NHEAD), 256, 0, stream>>>(
      qfull, KFULL, (long)S_LEN * KFULL, vupT, KVLORA, (long)V_DIM * KVLORA,
      attno, OUTW, (long)V_DIM, KVLORA, 0);

  // ---- final projection ----
  gemm_bt<float><<<dim3(HID / 128, S_LEN / 128, 1), 256, 0, stream>>>(
      attno, OUTW, 0, WoT, OUTW, 0, out, HID, 0, OUTW, 0);
}